// Round 17
// baseline (405.936 us; speedup 1.0000x reference)
//
#include <hip/hip_runtime.h>

// HashRoutedSSMLayer: B=8,S=2048,D=1024,N=256,H=512,E=8 — fp32 in/out.
// Round 21: scanA+scanC fused into ONE kernel via decoupled lookback:
// each chunk block computes (SA,SQ), publishes with agent-scope release
// flag (__threadfence + __hip_atomic_store — the sanctioned cross-XCD
// mechanism), acquire-spins on its <=11 predecessor flags (avg 4.5),
// composes h_in, re-scans and emits Yb. Deadlock-safe: 576 blocks, no LDS,
// low VGPR -> entire grid co-resident. Flags zeroed in k_route (stream-
// ordered, re-zeroed each graph replay). Everything else byte-identical to
// round 20 (GEMM champion BM=128 BN=64 BK=32 3-buf 4blk/CU; scatter+cvt
// fusion; nt loads/stores).

#define TOKS 16384
#define RPAD 16512      // TOKS + 128 pad rows for tile overread
#define DD   1024
#define NN   256
#define HH   512
#define MAXTILES  136   // sum ceil(ce/128) <= 128+8
#define MAXCHUNKS 576   // sum ceil(n_g/32) <= 512+64
#define CHUNK 32
#define CVTBLKS 12288   // weight-cvt blocks appended to the scatter launch

typedef short short8 __attribute__((ext_vector_type(8)));
typedef float floatx4 __attribute__((ext_vector_type(4)));
typedef _Float16 half_t;

#define AS_GLOBAL __attribute__((address_space(1)))
#define AS_LDS    __attribute__((address_space(3)))

__device__ __forceinline__ void gl_lds16(const void* g, void* l) {
    __builtin_amdgcn_global_load_lds((const AS_GLOBAL void*)g, (AS_LDS void*)l, 16, 0, 0);
}

__device__ __forceinline__ unsigned short f2bf(float f) {
    union { float f; unsigned u; } c; c.f = f;
    unsigned r = c.u + 0x7FFF + ((c.u >> 16) & 1);
    return (unsigned short)(r >> 16);
}
__device__ __forceinline__ int route_of(int token) {
    unsigned x = (unsigned)token;
    x ^= x >> 16; x *= 2246822507u; x ^= x >> 13; x *= 3266489909u; x ^= x >> 16;
    return (int)(x & 7u);
}
__device__ __forceinline__ float sigm(float v) { return 1.0f / (1.0f + __expf(-v)); }
__device__ __forceinline__ float ftanh(float v) {
    float e = __expf(2.0f * v);          // inf-safe: v>>0 -> 1, v<<0 -> -1
    return 1.0f - 2.0f / (e + 1.0f);
}

// ---------------- K1: per-row route histogram + flag zeroing ----------------
__global__ void k_route(const int* __restrict__ tok, int* __restrict__ cnt,
                        int* __restrict__ flags) {
    int b = blockIdx.x, tid = threadIdx.x;
    __shared__ int lc[256 * 8];
    int f = b * 256 + tid;                 // 0..2047 covers MAXCHUNKS=576
    if (f < MAXCHUNKS) flags[f] = 0;
    #pragma unroll
    for (int e = 0; e < 8; e++) lc[tid * 8 + e] = 0;
    #pragma unroll
    for (int i = 0; i < 8; i++) {
        int e = route_of(tok[b * 2048 + tid * 8 + i]);
        lc[tid * 8 + e]++;
    }
    __syncthreads();
    if (tid < 8) {
        int s = 0;
        for (int t = 0; t < 256; t++) s += lc[t * 8 + tid];
        cnt[b * 8 + tid] = s;
    }
}

// ---------------- K2+K3+cvt fused: scatter + offsets/tables + weight cvt ----------------
__global__ void k_scatter(const int* __restrict__ tok, const int* __restrict__ cnt,
                          int* __restrict__ perm,
                          int* __restrict__ tileE, int* __restrict__ tileS,
                          int* __restrict__ tileR,
                          int* __restrict__ cGrp, int* __restrict__ cStart,
                          int* __restrict__ cLen, int* __restrict__ gBase,
                          int* __restrict__ meta,
                          const float* __restrict__ Win, const float* __restrict__ Wsin,
                          const float* __restrict__ Wsout, const float* __restrict__ Wout,
                          unsigned short* __restrict__ W12, unsigned short* __restrict__ Wso,
                          unsigned short* __restrict__ Wo) {
    int blk = blockIdx.x, tid = threadIdx.x;
    if (blk >= 8) {
        // ---- weight conversion path (no barriers, block-uniform branch) ----
        const int C12 = 8 * 768 * 1024 / 4, CSO = 8 * 1024 * 512 / 4;
        int c = (blk - 8) * 256 + tid;
        floatx4 v; unsigned short* dst;
        if (c < C12) {
            int d = c * 4;
            int e = d / (768 * 1024);
            int rem = d - e * (768 * 1024);
            int r = rem >> 10, k = rem & 1023;
            const float* src = (r < 256) ? (Win + (((size_t)e * 256 + r) << 10) + k)
                                         : (Wsin + (((size_t)e * 512 + (r - 256)) << 10) + k);
            v = __builtin_nontemporal_load((const floatx4*)src);
            dst = W12 + d;
        } else if (c < C12 + CSO) {
            int d = (c - C12) * 4;
            v = __builtin_nontemporal_load((const floatx4*)(Wsout + d));
            dst = Wso + d;
        } else {
            int d = (c - C12 - CSO) * 4;
            v = __builtin_nontemporal_load((const floatx4*)(Wout + d));
            dst = Wo + d;
        }
        ushort4 o;
        o.x = f2bf(v[0]); o.y = f2bf(v[1]); o.z = f2bf(v[2]); o.w = f2bf(v[3]);
        *(ushort4*)dst = o;
        return;
    }
    // ---- scatter path (blocks 0-7) ----
    int b = blk;
    int lane = tid & 63, w = tid >> 6;
    __shared__ int sc[64], eoff[9], etile[9], gbs[65];
    __shared__ unsigned wsum[4][4];
    int r[8];
    int myc[8] = {0,0,0,0,0,0,0,0};
    #pragma unroll
    for (int i = 0; i < 8; i++) {
        int e = route_of(tok[b * 2048 + tid * 8 + i]);
        r[i] = e; myc[e]++;
    }
    if (tid < 64) sc[tid] = cnt[tid];
    __syncthreads();
    if (tid == 0) {
        int ce[8];
        for (int e = 0; e < 8; e++) {
            int s = 0;
            for (int b2 = 0; b2 < 8; b2++) s += sc[b2 * 8 + e];
            ce[e] = s;
        }
        eoff[0] = 0;
        for (int e = 0; e < 8; e++) eoff[e + 1] = eoff[e] + ce[e];
        if (b == 0) {
            etile[0] = 0;
            for (int e = 0; e < 8; e++) etile[e + 1] = etile[e] + (ce[e] + 127) / 128;
            meta[0] = etile[8];
            gbs[0] = 0;
            for (int g = 0; g < 64; g++) gbs[g + 1] = gbs[g] + (sc[g] + CHUNK - 1) / CHUNK;
            meta[1] = gbs[64];
        }
    }
    __syncthreads();
    unsigned p[4], v[4];
    #pragma unroll
    for (int k = 0; k < 4; k++) {
        p[k] = (unsigned)myc[2 * k] | ((unsigned)myc[2 * k + 1] << 16);
        v[k] = p[k];
    }
    #pragma unroll
    for (int off = 1; off < 64; off <<= 1) {
        #pragma unroll
        for (int k = 0; k < 4; k++) {
            unsigned o = __shfl_up(v[k], off, 64);
            if (lane >= off) v[k] += o;
        }
    }
    if (lane == 63) {
        #pragma unroll
        for (int k = 0; k < 4; k++) wsum[w][k] = v[k];
    }
    __syncthreads();
    unsigned add[4] = {0, 0, 0, 0};
    for (int ww = 0; ww < w; ww++)
        #pragma unroll
        for (int k = 0; k < 4; k++) add[k] += wsum[ww][k];
    int basep[8];
    #pragma unroll
    for (int e = 0; e < 8; e++) {
        int run = eoff[e];
        for (int b2 = 0; b2 < b; b2++) run += sc[b2 * 8 + e];
        unsigned ex = v[e >> 1] + add[e >> 1] - p[e >> 1];   // exclusive prefix
        basep[e] = run + (int)((e & 1) ? (ex >> 16) : (ex & 0xffffu));
    }
    #pragma unroll
    for (int i = 0; i < 8; i++) {
        int e = r[i];
        perm[basep[e]++] = b * 2048 + tid * 8 + i;
    }
    if (b == 0) {
        if (tid < 8) {   // 128-row tiles for expert tid
            int e = tid, st = eoff[e], c = eoff[e + 1] - eoff[e], t0 = etile[e];
            for (int i = 0, k = 0; i < c; i += 128, k++) {
                tileE[t0 + k] = e; tileS[t0 + k] = st + i;
                tileR[t0 + k] = (c - i < 128) ? (c - i) : 128;
            }
        }
        if (tid < 64) {  // chunks for group tid
            int g = tid, e = g & 7;
            int n = sc[g], base = gbs[g];
            int s0 = eoff[e];
            for (int b2 = 0; b2 < (g >> 3); b2++) s0 += sc[b2 * 8 + e];
            gBase[g] = base;
            for (int i = 0, c = 0; i < n; i += CHUNK, c++) {
                cGrp[base + c] = g;
                cStart[base + c] = s0 + i;
                cLen[base + c] = (n - i < CHUNK) ? (n - i) : CHUNK;
            }
        }
    }
}

// ---------------- K5: gather x into sorted bf16 rows + zero pads ----------------
__global__ void k_gather(const float* __restrict__ x, const int* __restrict__ perm,
                         unsigned short* __restrict__ Xs, unsigned short* __restrict__ SHb,
                         unsigned short* __restrict__ Yb) {
    int r = blockIdx.x, tid = threadIdx.x;
    if (r < TOKS) {
        int tok = perm[r];
        floatx4 v = __builtin_nontemporal_load(
            (const floatx4*)(x + (size_t)tok * 1024 + tid * 4));
        ushort4 o;
        o.x = f2bf(v[0]); o.y = f2bf(v[1]); o.z = f2bf(v[2]); o.w = f2bf(v[3]);
        *(ushort4*)(Xs + (size_t)r * 1024 + tid * 4) = o;
    } else {
        ushort4 z = {0, 0, 0, 0};
        *(ushort4*)(Xs + (size_t)r * 1024 + tid * 4) = z;
        if (tid < 128) *(ushort4*)(SHb + (size_t)r * 512 + tid * 4) = z;
        if (tid < 64)  *(ushort4*)(Yb + (size_t)r * 256 + tid * 4) = z;
    }
}

// ---------------- MFMA grouped GEMM, BM=128 BN=64 BK=32, 3-buf pipeline ----------------
// MODE 0: A=Xs (K=1024), B=W12: col0<256 -> Ub fp16; else silu -> SHb bf16
// MODE 1: A=SHb (K=512), B=Wso: region col0>>8 -> fp16 gates
// MODE 2: A=Yb (K=256),  B=Wo : scatter fp32 out via perm (nt stores)
// 256 thr / 4 waves (2M x 2N; per-wave 64x32, acc[4][2]); 3 gl_lds/thread/step,
// vmcnt(3) steady; LDS 36KB -> 4 blk/CU; T5 setprio around MFMA cluster.
template<int MODE, int KD>
__global__ __launch_bounds__(256, 4)
void k_mfma(const unsigned short* __restrict__ A, const unsigned short* __restrict__ Bw,
            const int* __restrict__ perm, const float* __restrict__ dparam,
            half_t* __restrict__ Ub, unsigned short* __restrict__ SHb,
            half_t* __restrict__ Aa, half_t* __restrict__ Wg,
            half_t* __restrict__ Cc, half_t* __restrict__ Sk,
            float* __restrict__ out,
            const int* __restrict__ tileE, const int* __restrict__ tileS,
            const int* __restrict__ tileR, const int* __restrict__ meta) {
    const int mt = blockIdx.x;
    if (mt >= meta[0]) return;
    const int e = tileE[mt], pos0 = tileS[mt], rows = tileR[mt];
    const int col0 = blockIdx.y * 64;
    const int tid = threadIdx.x;
    const int w = tid >> 6, lane = tid & 63, quad = lane >> 4, l15 = lane & 15;
    const int wm = w & 1, wn = w >> 1;          // 2M x 2N wave grid
    constexpr int NOUT = (MODE == 0) ? 768 : 1024;
    constexpr int NK = KD / 32;

    // triple-buffered: A [3][128][32], B [3][64][32] bf16 (12KB/buf set, 36KB)
    __shared__ unsigned short As[3][128 * 32];
    __shared__ unsigned short Bs[3][64 * 32];

    const int r0 = tid >> 2;                    // 0..63
    // pre-swizzled global chunk: chunk' = (tid&3) ^ ((row>>1)&3)
    const int c8s = ((tid & 3) ^ ((tid >> 3) & 3)) * 8;
    const unsigned short* ga = A + (size_t)(pos0 + r0) * KD + c8s;
    const unsigned short* gb = Bw + ((size_t)e * NOUT + col0 + r0) * KD + c8s;

    // fragment read offsets with matching XOR swizzle ((row>>1)&3 == (l15>>1)&3)
    const int sq = (quad ^ ((l15 >> 1) & 3)) * 8;
    int aoff[4], boff[2];
    #pragma unroll
    for (int i = 0; i < 4; i++) aoff[i] = (wm * 64 + i * 16 + l15) * 32 + sq;
    #pragma unroll
    for (int j = 0; j < 2; j++) boff[j] = (wn * 32 + j * 16 + l15) * 32 + sq;

    floatx4 acc[4][2] = {};

    // stage one BK=32 tile: A rows 0-63 and 64-127 (2 passes), B rows 0-63.
    #define STAGE(buf, k0) do { \
        gl_lds16(ga + (k0),                    As[buf] + w * 512); \
        gl_lds16(ga + (size_t)64 * KD + (k0),  As[buf] + 2048 + w * 512); \
        gl_lds16(gb + (k0),                    Bs[buf] + w * 512); \
    } while (0)

    STAGE(0, 0);                      // 3 outstanding
    STAGE(1, 32);                     // 6 outstanding
    int cur = 0, pre = 2;
    for (int kt = 0; kt < NK; kt++) {
        if (kt < NK - 1) {
            asm volatile("s_waitcnt vmcnt(3)" ::: "memory");   // stage(kt) landed
        } else {
            asm volatile("s_waitcnt vmcnt(0)" ::: "memory");
        }
        __builtin_amdgcn_s_barrier();          // all waves' stage(kt) landed; prev reads drained
        asm volatile("" ::: "memory");
        if (kt + 2 < NK) STAGE(pre, (kt + 2) * 32);   // 2-deep prefetch, distinct buffer
        short8 af[4], bf[2];
        #pragma unroll
        for (int i = 0; i < 4; i++) af[i] = *(const short8*)(As[cur] + aoff[i]);
        #pragma unroll
        for (int j = 0; j < 2; j++) bf[j] = *(const short8*)(Bs[cur] + boff[j]);
        __builtin_amdgcn_s_setprio(1);
        #pragma unroll
        for (int i = 0; i < 4; i++)
            #pragma unroll
            for (int j = 0; j < 2; j++)
                acc[i][j] = __builtin_amdgcn_mfma_f32_16x16x32_bf16(af[i], bf[j], acc[i][j], 0, 0, 0);
        __builtin_amdgcn_s_setprio(0);
        asm volatile("s_waitcnt lgkmcnt(0)" ::: "memory");
        __builtin_amdgcn_sched_barrier(0);
        cur = (cur == 2) ? 0 : cur + 1;
        pre = (pre == 2) ? 0 : pre + 1;
    }
    #undef STAGE
    asm volatile("" ::: "memory");             // keep epilogue loads out of the loop

    // epilogue: per 16x16 tile, col = l15 (n), row = quad*4 + reg (m)
    #pragma unroll
    for (int i = 0; i < 4; i++) {
        #pragma unroll
        for (int r = 0; r < 4; r++) {
            int m = wm * 64 + i * 16 + quad * 4 + r;
            if (m >= rows) continue;
            size_t row = (size_t)(pos0 + m);
            if (MODE == 0) {
                if (col0 < 256) {
                    #pragma unroll
                    for (int j = 0; j < 2; j++) {
                        int n = col0 + wn * 32 + j * 16 + l15;
                        Ub[row * 256 + n] = (half_t)acc[i][j][r];
                    }
                } else {
                    #pragma unroll
                    for (int j = 0; j < 2; j++) {
                        int n = col0 - 256 + wn * 32 + j * 16 + l15;
                        float v = acc[i][j][r];
                        SHb[row * 512 + n] = f2bf(v * sigm(v));
                    }
                }
            } else if (MODE == 1) {
                int region = col0 >> 8;  // block-uniform
                #pragma unroll
                for (int j = 0; j < 2; j++) {
                    int n0 = (col0 & 255) + wn * 32 + j * 16 + l15;
                    size_t idx = row * 256 + (size_t)n0;
                    float v = acc[i][j][r];
                    if (region == 0) {
                        Aa[idx] = (half_t)sigm(v);
                    } else if (region == 1) {
                        Wg[idx] = (half_t)(ftanh(v) * (float)Ub[idx]);
                    } else if (region == 2) {
                        Cc[idx] = (half_t)ftanh(v);
                    } else {
                        Sk[idx] = (half_t)(dparam[e * 256 + n0] * sigm(v) * (float)Ub[idx]);
                    }
                }
            } else {
                int tok = perm[row];
                #pragma unroll
                for (int j = 0; j < 2; j++) {
                    int n = col0 + wn * 32 + j * 16 + l15;
                    __builtin_nontemporal_store(acc[i][j][r], &out[(size_t)tok * 1024 + n]);
                }
            }
        }
    }
}

// ---------------- K8 fused: single-pass scan with decoupled lookback ----------------
// Phase A: compute chunk-local (SA,SQ); publish with agent-scope release flag.
// Lookback: acquire-spin on predecessor flags (same group, avg 4.5, max ~11;
// all 576 blocks co-resident -> no deadlock), compose h_in.
// Phase C: re-scan (Aa/Wg L3-hot) and emit Yb.
__global__ void k_scan(const half_t* __restrict__ Aa, const half_t* __restrict__ Wg,
                       const half_t* __restrict__ Cc, const half_t* __restrict__ Sk,
                       const int* __restrict__ cGrp, const int* __restrict__ cStart,
                       const int* __restrict__ cLen, const int* __restrict__ gBase,
                       const int* __restrict__ meta,
                       float* __restrict__ SA, float* __restrict__ SQ,
                       int* __restrict__ flags,
                       unsigned short* __restrict__ Yb) {
    int id = blockIdx.x;
    if (id >= meta[1]) return;
    int t = threadIdx.x;
    int g = cGrp[id], base = gBase[g], c = id - base;
    int s0 = cStart[id], L = cLen[id];
    size_t idx0 = (size_t)s0 * 256 + t;
    float p = 1.0f, q = 0.0f;
    if (L == CHUNK) {
        #pragma unroll
        for (int i = 0; i < CHUNK; i++) {
            size_t k = idx0 + (size_t)i * 256;
            float a = (float)Aa[k], ww = (float)Wg[k];
            q = a * q + ww;
            p *= a;
        }
    } else {
        size_t idx = idx0;
        for (int i = 0; i < L; i++) {
            float a = (float)Aa[idx], ww = (float)Wg[idx];
            q = a * q + ww;
            p *= a;
            idx += 256;
        }
    }
    SA[(size_t)id * 256 + t] = p;
    SQ[(size_t)id * 256 + t] = q;
    __syncthreads();               // all threads' SA/SQ stores drained (vmcnt 0)
    if (t == 0) {
        __threadfence();           // agent-scope fence: L2 writeback for cross-XCD
        __hip_atomic_store(&flags[id], 1, __ATOMIC_RELEASE, __HIP_MEMORY_SCOPE_AGENT);
    }
    // decoupled lookback: every thread acquires for itself (broadcast spin)
    float h = 0.0f;
    for (int j = 0; j < c; j++) {
        while (__hip_atomic_load(&flags[base + j], __ATOMIC_ACQUIRE,
                                 __HIP_MEMORY_SCOPE_AGENT) == 0)
            __builtin_amdgcn_s_sleep(8);
        size_t k = (size_t)(base + j) * 256 + t;
        h = SA[k] * h + SQ[k];
    }
    // phase C: re-scan with h_in, emit y
    if (L == CHUNK) {
        #pragma unroll
        for (int i = 0; i < CHUNK; i++) {
            size_t k = idx0 + (size_t)i * 256;
            float a = (float)Aa[k], ww = (float)Wg[k];
            float cc = (float)Cc[k], sk = (float)Sk[k];
            h = a * h + ww;
            Yb[k] = f2bf(cc * h + sk);
        }
    } else {
        size_t idx = idx0;
        for (int i = 0; i < L; i++) {
            float a = (float)Aa[idx], ww = (float)Wg[idx];
            float cc = (float)Cc[idx], sk = (float)Sk[idx];
            h = a * h + ww;
            Yb[idx] = f2bf(cc * h + sk);
            idx += 256;
        }
    }
}

extern "C" void kernel_launch(void* const* d_in, const int* in_sizes, int n_in,
                              void* d_out, int out_size, void* d_ws, size_t ws_size,
                              hipStream_t stream) {
    const float* xin   = (const float*)d_in[0];
    const int*   tok   = (const int*)d_in[1];
    const float* Win   = (const float*)d_in[2];
    const float* Wsin  = (const float*)d_in[3];
    const float* Wsout = (const float*)d_in[4];
    const float* Wout  = (const float*)d_in[5];
    const float* dpar  = (const float*)d_in[6];
    float* out = (float*)d_out;

    size_t off = 0;
    char* base = (char*)d_ws;
    auto alloc = [&](size_t bytes) -> void* {
        void* p = base + off;
        off += (bytes + 255) & ~(size_t)255;
        return p;
    };
    half_t*         Ub  = (half_t*)alloc((size_t)RPAD * NN * 2);
    unsigned short* SHb = (unsigned short*)alloc((size_t)RPAD * HH * 2);
    unsigned short* Xs  = (unsigned short*)alloc((size_t)RPAD * DD * 2);
    unsigned short* Yb  = (unsigned short*)alloc((size_t)RPAD * NN * 2);
    half_t* Aa = (half_t*)alloc((size_t)TOKS * NN * 2);
    half_t* Wg = (half_t*)alloc((size_t)TOKS * NN * 2);
    half_t* Cc = (half_t*)alloc((size_t)TOKS * NN * 2);
    half_t* Sk = (half_t*)alloc((size_t)TOKS * NN * 2);
    unsigned short* W12 = (unsigned short*)alloc((size_t)8 * 768 * 1024 * 2);
    unsigned short* Wso = (unsigned short*)alloc((size_t)8 * 1024 * 512 * 2);
    unsigned short* Wo  = (unsigned short*)alloc((size_t)8 * 1024 * 256 * 2);
    float* SA  = (float*)alloc((size_t)MAXCHUNKS * 256 * 4);
    float* SQ  = (float*)alloc((size_t)MAXCHUNKS * 256 * 4);
    int* perm   = (int*)alloc(TOKS * 4);
    int* cnt    = (int*)alloc(64 * 4);
    int* tileE  = (int*)alloc(MAXTILES * 4);
    int* tileS  = (int*)alloc(MAXTILES * 4);
    int* tileR  = (int*)alloc(MAXTILES * 4);
    int* cGrp   = (int*)alloc(MAXCHUNKS * 4);
    int* cStart = (int*)alloc(MAXCHUNKS * 4);
    int* cLen   = (int*)alloc(MAXCHUNKS * 4);
    int* gBase  = (int*)alloc(64 * 4);
    int* meta   = (int*)alloc(16 * 4);
    int* flags  = (int*)alloc(MAXCHUNKS * 4);

    k_route<<<8, 256, 0, stream>>>(tok, cnt, flags);
    k_scatter<<<8 + CVTBLKS, 256, 0, stream>>>(tok, cnt, perm, tileE, tileS, tileR,
                                               cGrp, cStart, cLen, gBase, meta,
                                               Win, Wsin, Wsout, Wout, W12, Wso, Wo);
    k_gather<<<RPAD, 256, 0, stream>>>(xin, perm, Xs, SHb, Yb);

    k_mfma<0, 1024><<<dim3(MAXTILES, 12), 256, 0, stream>>>(Xs, W12, perm, dpar,
        Ub, SHb, Aa, Wg, Cc, Sk, out, tileE, tileS, tileR, meta);
    k_mfma<1, 512><<<dim3(MAXTILES, 16), 256, 0, stream>>>(SHb, Wso, perm, dpar,
        Ub, SHb, Aa, Wg, Cc, Sk, out, tileE, tileS, tileR, meta);

    k_scan<<<MAXCHUNKS, 256, 0, stream>>>(Aa, Wg, Cc, Sk, cGrp, cStart, cLen,
                                          gBase, meta, SA, SQ, flags, Yb);

    k_mfma<2, 256><<<dim3(MAXTILES, 16), 256, 0, stream>>>(Yb, Wo, perm, dpar,
        Ub, SHb, Aa, Wg, Cc, Sk, out, tileE, tileS, tileR, meta);
}

// Round 18
// 318.143 us; speedup vs baseline: 1.2760x; 1.2760x over previous
//
#include <hip/hip_runtime.h>

// HashRoutedSSMLayer: B=8,S=2048,D=1024,N=256,H=512,E=8 — fp32 in/out.
// Round 22: FULL REVERT to round-20/16 champion (318.7us). Round-21's
// decoupled-lookback fused scan regressed to 112us/dispatch: agent-scope
// release/acquire spins cross non-coherent XCD L2s (~us-class per poll,
// serialized per predecessor) — the kernel boundary gives that ordering for
// free. Ledger: GEMM bracketed on every axis (tiles, occupancy, depth,
// persistence, XCD maps, swizzle, T5); aux fused to minimal launches;
// persistence and lookback both measured negative.

#define TOKS 16384
#define RPAD 16512      // TOKS + 128 pad rows for tile overread
#define DD   1024
#define NN   256
#define HH   512
#define MAXTILES  136   // sum ceil(ce/128) <= 128+8
#define MAXCHUNKS 576   // sum ceil(n_g/32) <= 512+64
#define CHUNK 32
#define CVTBLKS 12288   // weight-cvt blocks appended to the scatter launch

typedef short short8 __attribute__((ext_vector_type(8)));
typedef float floatx4 __attribute__((ext_vector_type(4)));
typedef _Float16 half_t;

#define AS_GLOBAL __attribute__((address_space(1)))
#define AS_LDS    __attribute__((address_space(3)))

__device__ __forceinline__ void gl_lds16(const void* g, void* l) {
    __builtin_amdgcn_global_load_lds((const AS_GLOBAL void*)g, (AS_LDS void*)l, 16, 0, 0);
}

__device__ __forceinline__ unsigned short f2bf(float f) {
    union { float f; unsigned u; } c; c.f = f;
    unsigned r = c.u + 0x7FFF + ((c.u >> 16) & 1);
    return (unsigned short)(r >> 16);
}
__device__ __forceinline__ int route_of(int token) {
    unsigned x = (unsigned)token;
    x ^= x >> 16; x *= 2246822507u; x ^= x >> 13; x *= 3266489909u; x ^= x >> 16;
    return (int)(x & 7u);
}
__device__ __forceinline__ float sigm(float v) { return 1.0f / (1.0f + __expf(-v)); }
__device__ __forceinline__ float ftanh(float v) {
    float e = __expf(2.0f * v);          // inf-safe: v>>0 -> 1, v<<0 -> -1
    return 1.0f - 2.0f / (e + 1.0f);
}

// ---------------- K1: per-row route histogram ----------------
__global__ void k_route(const int* __restrict__ tok, int* __restrict__ cnt) {
    int b = blockIdx.x, tid = threadIdx.x;
    __shared__ int lc[256 * 8];
    #pragma unroll
    for (int e = 0; e < 8; e++) lc[tid * 8 + e] = 0;
    #pragma unroll
    for (int i = 0; i < 8; i++) {
        int e = route_of(tok[b * 2048 + tid * 8 + i]);
        lc[tid * 8 + e]++;
    }
    __syncthreads();
    if (tid < 8) {
        int s = 0;
        for (int t = 0; t < 256; t++) s += lc[t * 8 + tid];
        cnt[b * 8 + tid] = s;
    }
}

// ---------------- K2+K3+cvt fused: scatter + offsets/tables + weight cvt ----------------
// Blocks 0-7: counting-sort scatter (block 0 also writes tile/chunk/meta).
// Blocks 8..8+CVTBLKS-1: fp32->bf16 weight conversion (independent work that
// runs concurrently — previously 97% of CUs idled during route/scatter).
__global__ void k_scatter(const int* __restrict__ tok, const int* __restrict__ cnt,
                          int* __restrict__ perm,
                          int* __restrict__ tileE, int* __restrict__ tileS,
                          int* __restrict__ tileR,
                          int* __restrict__ cGrp, int* __restrict__ cStart,
                          int* __restrict__ cLen, int* __restrict__ gBase,
                          int* __restrict__ meta,
                          const float* __restrict__ Win, const float* __restrict__ Wsin,
                          const float* __restrict__ Wsout, const float* __restrict__ Wout,
                          unsigned short* __restrict__ W12, unsigned short* __restrict__ Wso,
                          unsigned short* __restrict__ Wo) {
    int blk = blockIdx.x, tid = threadIdx.x;
    if (blk >= 8) {
        // ---- weight conversion path (no barriers, block-uniform branch) ----
        const int C12 = 8 * 768 * 1024 / 4, CSO = 8 * 1024 * 512 / 4;
        int c = (blk - 8) * 256 + tid;
        floatx4 v; unsigned short* dst;
        if (c < C12) {
            int d = c * 4;
            int e = d / (768 * 1024);
            int rem = d - e * (768 * 1024);
            int r = rem >> 10, k = rem & 1023;
            const float* src = (r < 256) ? (Win + (((size_t)e * 256 + r) << 10) + k)
                                         : (Wsin + (((size_t)e * 512 + (r - 256)) << 10) + k);
            v = __builtin_nontemporal_load((const floatx4*)src);
            dst = W12 + d;
        } else if (c < C12 + CSO) {
            int d = (c - C12) * 4;
            v = __builtin_nontemporal_load((const floatx4*)(Wsout + d));
            dst = Wso + d;
        } else {
            int d = (c - C12 - CSO) * 4;
            v = __builtin_nontemporal_load((const floatx4*)(Wout + d));
            dst = Wo + d;
        }
        ushort4 o;
        o.x = f2bf(v[0]); o.y = f2bf(v[1]); o.z = f2bf(v[2]); o.w = f2bf(v[3]);
        *(ushort4*)dst = o;
        return;
    }
    // ---- scatter path (blocks 0-7) ----
    int b = blk;
    int lane = tid & 63, w = tid >> 6;
    __shared__ int sc[64], eoff[9], etile[9], gbs[65];
    __shared__ unsigned wsum[4][4];
    int r[8];
    int myc[8] = {0,0,0,0,0,0,0,0};
    #pragma unroll
    for (int i = 0; i < 8; i++) {
        int e = route_of(tok[b * 2048 + tid * 8 + i]);
        r[i] = e; myc[e]++;
    }
    if (tid < 64) sc[tid] = cnt[tid];
    __syncthreads();
    if (tid == 0) {
        int ce[8];
        for (int e = 0; e < 8; e++) {
            int s = 0;
            for (int b2 = 0; b2 < 8; b2++) s += sc[b2 * 8 + e];
            ce[e] = s;
        }
        eoff[0] = 0;
        for (int e = 0; e < 8; e++) eoff[e + 1] = eoff[e] + ce[e];
        if (b == 0) {
            etile[0] = 0;
            for (int e = 0; e < 8; e++) etile[e + 1] = etile[e] + (ce[e] + 127) / 128;
            meta[0] = etile[8];
            gbs[0] = 0;
            for (int g = 0; g < 64; g++) gbs[g + 1] = gbs[g] + (sc[g] + CHUNK - 1) / CHUNK;
            meta[1] = gbs[64];
        }
    }
    __syncthreads();
    unsigned p[4], v[4];
    #pragma unroll
    for (int k = 0; k < 4; k++) {
        p[k] = (unsigned)myc[2 * k] | ((unsigned)myc[2 * k + 1] << 16);
        v[k] = p[k];
    }
    #pragma unroll
    for (int off = 1; off < 64; off <<= 1) {
        #pragma unroll
        for (int k = 0; k < 4; k++) {
            unsigned o = __shfl_up(v[k], off, 64);
            if (lane >= off) v[k] += o;
        }
    }
    if (lane == 63) {
        #pragma unroll
        for (int k = 0; k < 4; k++) wsum[w][k] = v[k];
    }
    __syncthreads();
    unsigned add[4] = {0, 0, 0, 0};
    for (int ww = 0; ww < w; ww++)
        #pragma unroll
        for (int k = 0; k < 4; k++) add[k] += wsum[ww][k];
    int basep[8];
    #pragma unroll
    for (int e = 0; e < 8; e++) {
        int run = eoff[e];
        for (int b2 = 0; b2 < b; b2++) run += sc[b2 * 8 + e];
        unsigned ex = v[e >> 1] + add[e >> 1] - p[e >> 1];   // exclusive prefix
        basep[e] = run + (int)((e & 1) ? (ex >> 16) : (ex & 0xffffu));
    }
    #pragma unroll
    for (int i = 0; i < 8; i++) {
        int e = r[i];
        perm[basep[e]++] = b * 2048 + tid * 8 + i;
    }
    if (b == 0) {
        if (tid < 8) {   // 128-row tiles for expert tid
            int e = tid, st = eoff[e], c = eoff[e + 1] - eoff[e], t0 = etile[e];
            for (int i = 0, k = 0; i < c; i += 128, k++) {
                tileE[t0 + k] = e; tileS[t0 + k] = st + i;
                tileR[t0 + k] = (c - i < 128) ? (c - i) : 128;
            }
        }
        if (tid < 64) {  // chunks for group tid
            int g = tid, e = g & 7;
            int n = sc[g], base = gbs[g];
            int s0 = eoff[e];
            for (int b2 = 0; b2 < (g >> 3); b2++) s0 += sc[b2 * 8 + e];
            gBase[g] = base;
            for (int i = 0, c = 0; i < n; i += CHUNK, c++) {
                cGrp[base + c] = g;
                cStart[base + c] = s0 + i;
                cLen[base + c] = (n - i < CHUNK) ? (n - i) : CHUNK;
            }
        }
    }
}

// ---------------- K5: gather x into sorted bf16 rows + zero pads ----------------
__global__ void k_gather(const float* __restrict__ x, const int* __restrict__ perm,
                         unsigned short* __restrict__ Xs, unsigned short* __restrict__ SHb,
                         unsigned short* __restrict__ Yb) {
    int r = blockIdx.x, tid = threadIdx.x;
    if (r < TOKS) {
        int tok = perm[r];
        floatx4 v = __builtin_nontemporal_load(
            (const floatx4*)(x + (size_t)tok * 1024 + tid * 4));
        ushort4 o;
        o.x = f2bf(v[0]); o.y = f2bf(v[1]); o.z = f2bf(v[2]); o.w = f2bf(v[3]);
        *(ushort4*)(Xs + (size_t)r * 1024 + tid * 4) = o;
    } else {
        ushort4 z = {0, 0, 0, 0};
        *(ushort4*)(Xs + (size_t)r * 1024 + tid * 4) = z;
        if (tid < 128) *(ushort4*)(SHb + (size_t)r * 512 + tid * 4) = z;
        if (tid < 64)  *(ushort4*)(Yb + (size_t)r * 256 + tid * 4) = z;
    }
}

// ---------------- MFMA grouped GEMM, BM=128 BN=64 BK=32, 3-buf pipeline ----------------
// MODE 0: A=Xs (K=1024), B=W12: col0<256 -> Ub fp16; else silu -> SHb bf16
// MODE 1: A=SHb (K=512), B=Wso: region col0>>8 -> fp16 gates
// MODE 2: A=Yb (K=256),  B=Wo : scatter fp32 out via perm (nt stores)
// 256 thr / 4 waves (2M x 2N; per-wave 64x32, acc[4][2]); 3 gl_lds/thread/step,
// vmcnt(3) steady; LDS 36KB -> 4 blk/CU; T5 setprio around MFMA cluster.
template<int MODE, int KD>
__global__ __launch_bounds__(256, 4)
void k_mfma(const unsigned short* __restrict__ A, const unsigned short* __restrict__ Bw,
            const int* __restrict__ perm, const float* __restrict__ dparam,
            half_t* __restrict__ Ub, unsigned short* __restrict__ SHb,
            half_t* __restrict__ Aa, half_t* __restrict__ Wg,
            half_t* __restrict__ Cc, half_t* __restrict__ Sk,
            float* __restrict__ out,
            const int* __restrict__ tileE, const int* __restrict__ tileS,
            const int* __restrict__ tileR, const int* __restrict__ meta) {
    const int mt = blockIdx.x;
    if (mt >= meta[0]) return;
    const int e = tileE[mt], pos0 = tileS[mt], rows = tileR[mt];
    const int col0 = blockIdx.y * 64;
    const int tid = threadIdx.x;
    const int w = tid >> 6, lane = tid & 63, quad = lane >> 4, l15 = lane & 15;
    const int wm = w & 1, wn = w >> 1;          // 2M x 2N wave grid
    constexpr int NOUT = (MODE == 0) ? 768 : 1024;
    constexpr int NK = KD / 32;

    // triple-buffered: A [3][128][32], B [3][64][32] bf16 (12KB/buf set, 36KB)
    __shared__ unsigned short As[3][128 * 32];
    __shared__ unsigned short Bs[3][64 * 32];

    const int r0 = tid >> 2;                    // 0..63
    // pre-swizzled global chunk: chunk' = (tid&3) ^ ((row>>1)&3)
    const int c8s = ((tid & 3) ^ ((tid >> 3) & 3)) * 8;
    const unsigned short* ga = A + (size_t)(pos0 + r0) * KD + c8s;
    const unsigned short* gb = Bw + ((size_t)e * NOUT + col0 + r0) * KD + c8s;

    // fragment read offsets with matching XOR swizzle ((row>>1)&3 == (l15>>1)&3)
    const int sq = (quad ^ ((l15 >> 1) & 3)) * 8;
    int aoff[4], boff[2];
    #pragma unroll
    for (int i = 0; i < 4; i++) aoff[i] = (wm * 64 + i * 16 + l15) * 32 + sq;
    #pragma unroll
    for (int j = 0; j < 2; j++) boff[j] = (wn * 32 + j * 16 + l15) * 32 + sq;

    floatx4 acc[4][2] = {};

    // stage one BK=32 tile: A rows 0-63 and 64-127 (2 passes), B rows 0-63.
    #define STAGE(buf, k0) do { \
        gl_lds16(ga + (k0),                    As[buf] + w * 512); \
        gl_lds16(ga + (size_t)64 * KD + (k0),  As[buf] + 2048 + w * 512); \
        gl_lds16(gb + (k0),                    Bs[buf] + w * 512); \
    } while (0)

    STAGE(0, 0);                      // 3 outstanding
    STAGE(1, 32);                     // 6 outstanding
    int cur = 0, pre = 2;
    for (int kt = 0; kt < NK; kt++) {
        if (kt < NK - 1) {
            asm volatile("s_waitcnt vmcnt(3)" ::: "memory");   // stage(kt) landed
        } else {
            asm volatile("s_waitcnt vmcnt(0)" ::: "memory");
        }
        __builtin_amdgcn_s_barrier();          // all waves' stage(kt) landed; prev reads drained
        asm volatile("" ::: "memory");
        if (kt + 2 < NK) STAGE(pre, (kt + 2) * 32);   // 2-deep prefetch, distinct buffer
        short8 af[4], bf[2];
        #pragma unroll
        for (int i = 0; i < 4; i++) af[i] = *(const short8*)(As[cur] + aoff[i]);
        #pragma unroll
        for (int j = 0; j < 2; j++) bf[j] = *(const short8*)(Bs[cur] + boff[j]);
        __builtin_amdgcn_s_setprio(1);
        #pragma unroll
        for (int i = 0; i < 4; i++)
            #pragma unroll
            for (int j = 0; j < 2; j++)
                acc[i][j] = __builtin_amdgcn_mfma_f32_16x16x32_bf16(af[i], bf[j], acc[i][j], 0, 0, 0);
        __builtin_amdgcn_s_setprio(0);
        asm volatile("s_waitcnt lgkmcnt(0)" ::: "memory");
        __builtin_amdgcn_sched_barrier(0);
        cur = (cur == 2) ? 0 : cur + 1;
        pre = (pre == 2) ? 0 : pre + 1;
    }
    #undef STAGE
    asm volatile("" ::: "memory");             // keep epilogue loads out of the loop

    // epilogue: per 16x16 tile, col = l15 (n), row = quad*4 + reg (m)
    #pragma unroll
    for (int i = 0; i < 4; i++) {
        #pragma unroll
        for (int r = 0; r < 4; r++) {
            int m = wm * 64 + i * 16 + quad * 4 + r;
            if (m >= rows) continue;
            size_t row = (size_t)(pos0 + m);
            if (MODE == 0) {
                if (col0 < 256) {
                    #pragma unroll
                    for (int j = 0; j < 2; j++) {
                        int n = col0 + wn * 32 + j * 16 + l15;
                        Ub[row * 256 + n] = (half_t)acc[i][j][r];
                    }
                } else {
                    #pragma unroll
                    for (int j = 0; j < 2; j++) {
                        int n = col0 - 256 + wn * 32 + j * 16 + l15;
                        float v = acc[i][j][r];
                        SHb[row * 512 + n] = f2bf(v * sigm(v));
                    }
                }
            } else if (MODE == 1) {
                int region = col0 >> 8;  // block-uniform
                #pragma unroll
                for (int j = 0; j < 2; j++) {
                    int n0 = (col0 & 255) + wn * 32 + j * 16 + l15;
                    size_t idx = row * 256 + (size_t)n0;
                    float v = acc[i][j][r];
                    if (region == 0) {
                        Aa[idx] = (half_t)sigm(v);
                    } else if (region == 1) {
                        Wg[idx] = (half_t)(ftanh(v) * (float)Ub[idx]);
                    } else if (region == 2) {
                        Cc[idx] = (half_t)ftanh(v);
                    } else {
                        Sk[idx] = (half_t)(dparam[e * 256 + n0] * sigm(v) * (float)Ub[idx]);
                    }
                }
            } else {
                int tok = perm[row];
                #pragma unroll
                for (int j = 0; j < 2; j++) {
                    int n = col0 + wn * 32 + j * 16 + l15;
                    __builtin_nontemporal_store(acc[i][j][r], &out[(size_t)tok * 1024 + n]);
                }
            }
        }
    }
}

// ---------------- K8a: chunk-local affine composition ----------------
__global__ void k_scanA(const half_t* __restrict__ Aa, const half_t* __restrict__ Wg,
                        const int* __restrict__ cStart, const int* __restrict__ cLen,
                        const int* __restrict__ meta,
                        float* __restrict__ SA, float* __restrict__ SQ) {
    int id = blockIdx.x;
    if (id >= meta[1]) return;
    int t = threadIdx.x;
    int s0 = cStart[id], L = cLen[id];
    size_t idx = (size_t)s0 * 256 + t;
    float p = 1.0f, q = 0.0f;
    if (L == CHUNK) {
        #pragma unroll
        for (int i = 0; i < CHUNK; i++) {
            float a = (float)Aa[idx + (size_t)i * 256], ww = (float)Wg[idx + (size_t)i * 256];
            q = a * q + ww;
            p *= a;
        }
    } else {
        for (int i = 0; i < L; i++) {
            float a = (float)Aa[idx], ww = (float)Wg[idx];
            q = a * q + ww;
            p *= a;
            idx += 256;
        }
    }
    SA[(size_t)id * 256 + t] = p;
    SQ[(size_t)id * 256 + t] = q;
}

// ---------------- K8bc: h_in recompose (folded scanB) + re-scan, emit y ----------------
__global__ void k_scanC(const half_t* __restrict__ Aa, const half_t* __restrict__ Wg,
                        const half_t* __restrict__ Cc, const half_t* __restrict__ Sk,
                        const int* __restrict__ cGrp, const int* __restrict__ cStart,
                        const int* __restrict__ cLen, const int* __restrict__ gBase,
                        const float* __restrict__ SA, const float* __restrict__ SQ,
                        const int* __restrict__ meta,
                        unsigned short* __restrict__ Yb) {
    int id = blockIdx.x;
    if (id >= meta[1]) return;
    int t = threadIdx.x;
    int g = cGrp[id];
    int base = gBase[g];
    int c = id - base;
    float h = 0.0f;
    for (int j = 0; j < c; j++) {
        size_t k = (size_t)(base + j) * 256 + t;
        h = SA[k] * h + SQ[k];
    }
    int s0 = cStart[id], L = cLen[id];
    size_t idx = (size_t)s0 * 256 + t;
    if (L == CHUNK) {
        #pragma unroll
        for (int i = 0; i < CHUNK; i++) {
            size_t k = idx + (size_t)i * 256;
            float a = (float)Aa[k], ww = (float)Wg[k];
            float cc = (float)Cc[k], sk = (float)Sk[k];
            h = a * h + ww;
            Yb[k] = f2bf(cc * h + sk);
        }
    } else {
        for (int i = 0; i < L; i++) {
            float a = (float)Aa[idx], ww = (float)Wg[idx];
            float cc = (float)Cc[idx], sk = (float)Sk[idx];
            h = a * h + ww;
            Yb[idx] = f2bf(cc * h + sk);
            idx += 256;
        }
    }
}

extern "C" void kernel_launch(void* const* d_in, const int* in_sizes, int n_in,
                              void* d_out, int out_size, void* d_ws, size_t ws_size,
                              hipStream_t stream) {
    const float* xin   = (const float*)d_in[0];
    const int*   tok   = (const int*)d_in[1];
    const float* Win   = (const float*)d_in[2];
    const float* Wsin  = (const float*)d_in[3];
    const float* Wsout = (const float*)d_in[4];
    const float* Wout  = (const float*)d_in[5];
    const float* dpar  = (const float*)d_in[6];
    float* out = (float*)d_out;

    size_t off = 0;
    char* base = (char*)d_ws;
    auto alloc = [&](size_t bytes) -> void* {
        void* p = base + off;
        off += (bytes + 255) & ~(size_t)255;
        return p;
    };
    half_t*         Ub  = (half_t*)alloc((size_t)RPAD * NN * 2);
    unsigned short* SHb = (unsigned short*)alloc((size_t)RPAD * HH * 2);
    unsigned short* Xs  = (unsigned short*)alloc((size_t)RPAD * DD * 2);
    unsigned short* Yb  = (unsigned short*)alloc((size_t)RPAD * NN * 2);
    half_t* Aa = (half_t*)alloc((size_t)TOKS * NN * 2);
    half_t* Wg = (half_t*)alloc((size_t)TOKS * NN * 2);
    half_t* Cc = (half_t*)alloc((size_t)TOKS * NN * 2);
    half_t* Sk = (half_t*)alloc((size_t)TOKS * NN * 2);
    unsigned short* W12 = (unsigned short*)alloc((size_t)8 * 768 * 1024 * 2);
    unsigned short* Wso = (unsigned short*)alloc((size_t)8 * 1024 * 512 * 2);
    unsigned short* Wo  = (unsigned short*)alloc((size_t)8 * 1024 * 256 * 2);
    float* SA  = (float*)alloc((size_t)MAXCHUNKS * 256 * 4);
    float* SQ  = (float*)alloc((size_t)MAXCHUNKS * 256 * 4);
    int* perm   = (int*)alloc(TOKS * 4);
    int* cnt    = (int*)alloc(64 * 4);
    int* tileE  = (int*)alloc(MAXTILES * 4);
    int* tileS  = (int*)alloc(MAXTILES * 4);
    int* tileR  = (int*)alloc(MAXTILES * 4);
    int* cGrp   = (int*)alloc(MAXCHUNKS * 4);
    int* cStart = (int*)alloc(MAXCHUNKS * 4);
    int* cLen   = (int*)alloc(MAXCHUNKS * 4);
    int* gBase  = (int*)alloc(64 * 4);
    int* meta   = (int*)alloc(16 * 4);

    k_route<<<8, 256, 0, stream>>>(tok, cnt);
    k_scatter<<<8 + CVTBLKS, 256, 0, stream>>>(tok, cnt, perm, tileE, tileS, tileR,
                                               cGrp, cStart, cLen, gBase, meta,
                                               Win, Wsin, Wsout, Wout, W12, Wso, Wo);
    k_gather<<<RPAD, 256, 0, stream>>>(xin, perm, Xs, SHb, Yb);

    k_mfma<0, 1024><<<dim3(MAXTILES, 12), 256, 0, stream>>>(Xs, W12, perm, dpar,
        Ub, SHb, Aa, Wg, Cc, Sk, out, tileE, tileS, tileR, meta);
    k_mfma<1, 512><<<dim3(MAXTILES, 16), 256, 0, stream>>>(SHb, Wso, perm, dpar,
        Ub, SHb, Aa, Wg, Cc, Sk, out, tileE, tileS, tileR, meta);

    k_scanA<<<MAXCHUNKS, 256, 0, stream>>>(Aa, Wg, cStart, cLen, meta, SA, SQ);
    k_scanC<<<MAXCHUNKS, 256, 0, stream>>>(Aa, Wg, Cc, Sk, cGrp, cStart, cLen,
                                           gBase, SA, SQ, meta, Yb);

    k_mfma<2, 256><<<dim3(MAXTILES, 16), 256, 0, stream>>>(Yb, Wo, perm, dpar,
        Ub, SHb, Aa, Wg, Cc, Sk, out, tileE, tileS, tileR, meta);
}

// Round 19
// 317.226 us; speedup vs baseline: 1.2796x; 1.0029x over previous
//
#include <hip/hip_runtime.h>

// HashRoutedSSMLayer: B=8,S=2048,D=1024,N=256,H=512,E=8 — fp32 in/out.
// Round 23: k_route launch DELETED — each scatter block recomputes the full
// 64-entry (row,expert) histogram itself (thread t hashes 64 tokens of row
// t>>5; LDS reduce). Extra ~500 VALU ops/thread in 8 blocks, fully hidden
// under the 12288 concurrent cvt blocks (~20us BW work). One less launch +
// gap. Everything downstream byte-identical to round 22 champion (318.1us):
// GEMM BM=128 BN=64 BK=32 3-buf 2-deep 1-barrier 4blk/CU nt-stores,
// scatter+cvt fusion, gather, scanA + scanC(folded scanB).

#define TOKS 16384
#define RPAD 16512      // TOKS + 128 pad rows for tile overread
#define DD   1024
#define NN   256
#define HH   512
#define MAXTILES  136   // sum ceil(ce/128) <= 128+8
#define MAXCHUNKS 576   // sum ceil(n_g/32) <= 512+64
#define CHUNK 32
#define CVTBLKS 12288   // weight-cvt blocks appended to the scatter launch

typedef short short8 __attribute__((ext_vector_type(8)));
typedef float floatx4 __attribute__((ext_vector_type(4)));
typedef _Float16 half_t;

#define AS_GLOBAL __attribute__((address_space(1)))
#define AS_LDS    __attribute__((address_space(3)))

__device__ __forceinline__ void gl_lds16(const void* g, void* l) {
    __builtin_amdgcn_global_load_lds((const AS_GLOBAL void*)g, (AS_LDS void*)l, 16, 0, 0);
}

__device__ __forceinline__ unsigned short f2bf(float f) {
    union { float f; unsigned u; } c; c.f = f;
    unsigned r = c.u + 0x7FFF + ((c.u >> 16) & 1);
    return (unsigned short)(r >> 16);
}
__device__ __forceinline__ int route_of(int token) {
    unsigned x = (unsigned)token;
    x ^= x >> 16; x *= 2246822507u; x ^= x >> 13; x *= 3266489909u; x ^= x >> 16;
    return (int)(x & 7u);
}
__device__ __forceinline__ float sigm(float v) { return 1.0f / (1.0f + __expf(-v)); }
__device__ __forceinline__ float ftanh(float v) {
    float e = __expf(2.0f * v);          // inf-safe: v>>0 -> 1, v<<0 -> -1
    return 1.0f - 2.0f / (e + 1.0f);
}

// ---------------- K1+K2+K3+cvt fused: histogram + scatter + tables + weight cvt ----------------
// Blocks 0-7: per-block full histogram (thread t hashes 64 tokens of row
// t>>5, slice t&31 -> LDS reduce to sc[64]); then counting-sort scatter
// (block 0 also writes tile/chunk/meta tables).
// Blocks 8..: fp32->bf16 weight conversion (independent, concurrent).
__global__ void k_scatter(const int* __restrict__ tok,
                          int* __restrict__ perm,
                          int* __restrict__ tileE, int* __restrict__ tileS,
                          int* __restrict__ tileR,
                          int* __restrict__ cGrp, int* __restrict__ cStart,
                          int* __restrict__ cLen, int* __restrict__ gBase,
                          int* __restrict__ meta,
                          const float* __restrict__ Win, const float* __restrict__ Wsin,
                          const float* __restrict__ Wsout, const float* __restrict__ Wout,
                          unsigned short* __restrict__ W12, unsigned short* __restrict__ Wso,
                          unsigned short* __restrict__ Wo) {
    int blk = blockIdx.x, tid = threadIdx.x;
    if (blk >= 8) {
        // ---- weight conversion path (no barriers, block-uniform branch) ----
        const int C12 = 8 * 768 * 1024 / 4, CSO = 8 * 1024 * 512 / 4;
        int c = (blk - 8) * 256 + tid;
        floatx4 v; unsigned short* dst;
        if (c < C12) {
            int d = c * 4;
            int e = d / (768 * 1024);
            int rem = d - e * (768 * 1024);
            int r = rem >> 10, k = rem & 1023;
            const float* src = (r < 256) ? (Win + (((size_t)e * 256 + r) << 10) + k)
                                         : (Wsin + (((size_t)e * 512 + (r - 256)) << 10) + k);
            v = __builtin_nontemporal_load((const floatx4*)src);
            dst = W12 + d;
        } else if (c < C12 + CSO) {
            int d = (c - C12) * 4;
            v = __builtin_nontemporal_load((const floatx4*)(Wsout + d));
            dst = Wso + d;
        } else {
            int d = (c - C12 - CSO) * 4;
            v = __builtin_nontemporal_load((const floatx4*)(Wout + d));
            dst = Wo + d;
        }
        ushort4 o;
        o.x = f2bf(v[0]); o.y = f2bf(v[1]); o.z = f2bf(v[2]); o.w = f2bf(v[3]);
        *(ushort4*)dst = o;
        return;
    }
    // ---- scatter path (blocks 0-7) ----
    int b = blk;
    int lane = tid & 63, w = tid >> 6;
    __shared__ int hh[8][8][32];       // [row][expert][slice] partial counts (8KB)
    __shared__ int sc[64], eoff[9], etile[9], gbs[65];
    __shared__ unsigned wsum[4][4];

    // phase 0: full-grid histogram — thread t covers row t>>5, tokens (t&31)*64..+63
    {
        int hr = tid >> 5, hs = tid & 31;
        const int* tp = tok + hr * 2048 + hs * 64;
        int hc[8] = {0,0,0,0,0,0,0,0};
        #pragma unroll 8
        for (int i = 0; i < 64; i++) hc[route_of(tp[i])]++;
        #pragma unroll
        for (int e = 0; e < 8; e++) hh[hr][e][hs] = hc[e];
    }
    // per-thread own-row counts for the scatter rank (token/time order)
    int r[8];
    int myc[8] = {0,0,0,0,0,0,0,0};
    #pragma unroll
    for (int i = 0; i < 8; i++) {
        int e = route_of(tok[b * 2048 + tid * 8 + i]);
        r[i] = e; myc[e]++;
    }
    __syncthreads();
    if (tid < 64) {                    // sc[row*8+e] = sum over 32 slices
        int row = tid >> 3, e = tid & 7, s = 0;
        #pragma unroll
        for (int s2 = 0; s2 < 32; s2++) s += hh[row][e][s2];
        sc[tid] = s;
    }
    __syncthreads();
    if (tid == 0) {
        int ce[8];
        for (int e = 0; e < 8; e++) {
            int s = 0;
            for (int b2 = 0; b2 < 8; b2++) s += sc[b2 * 8 + e];
            ce[e] = s;
        }
        eoff[0] = 0;
        for (int e = 0; e < 8; e++) eoff[e + 1] = eoff[e] + ce[e];
        if (b == 0) {
            etile[0] = 0;
            for (int e = 0; e < 8; e++) etile[e + 1] = etile[e] + (ce[e] + 127) / 128;
            meta[0] = etile[8];
            gbs[0] = 0;
            for (int g = 0; g < 64; g++) gbs[g + 1] = gbs[g] + (sc[g] + CHUNK - 1) / CHUNK;
            meta[1] = gbs[64];
        }
    }
    __syncthreads();
    unsigned p[4], v[4];
    #pragma unroll
    for (int k = 0; k < 4; k++) {
        p[k] = (unsigned)myc[2 * k] | ((unsigned)myc[2 * k + 1] << 16);
        v[k] = p[k];
    }
    #pragma unroll
    for (int off = 1; off < 64; off <<= 1) {
        #pragma unroll
        for (int k = 0; k < 4; k++) {
            unsigned o = __shfl_up(v[k], off, 64);
            if (lane >= off) v[k] += o;
        }
    }
    if (lane == 63) {
        #pragma unroll
        for (int k = 0; k < 4; k++) wsum[w][k] = v[k];
    }
    __syncthreads();
    unsigned add[4] = {0, 0, 0, 0};
    for (int ww = 0; ww < w; ww++)
        #pragma unroll
        for (int k = 0; k < 4; k++) add[k] += wsum[ww][k];
    int basep[8];
    #pragma unroll
    for (int e = 0; e < 8; e++) {
        int run = eoff[e];
        for (int b2 = 0; b2 < b; b2++) run += sc[b2 * 8 + e];
        unsigned ex = v[e >> 1] + add[e >> 1] - p[e >> 1];   // exclusive prefix
        basep[e] = run + (int)((e & 1) ? (ex >> 16) : (ex & 0xffffu));
    }
    #pragma unroll
    for (int i = 0; i < 8; i++) {
        int e = r[i];
        perm[basep[e]++] = b * 2048 + tid * 8 + i;
    }
    if (b == 0) {
        if (tid < 8) {   // 128-row tiles for expert tid
            int e = tid, st = eoff[e], c = eoff[e + 1] - eoff[e], t0 = etile[e];
            for (int i = 0, k = 0; i < c; i += 128, k++) {
                tileE[t0 + k] = e; tileS[t0 + k] = st + i;
                tileR[t0 + k] = (c - i < 128) ? (c - i) : 128;
            }
        }
        if (tid < 64) {  // chunks for group tid
            int g = tid, e = g & 7;
            int n = sc[g], base = gbs[g];
            int s0 = eoff[e];
            for (int b2 = 0; b2 < (g >> 3); b2++) s0 += sc[b2 * 8 + e];
            gBase[g] = base;
            for (int i = 0, c = 0; i < n; i += CHUNK, c++) {
                cGrp[base + c] = g;
                cStart[base + c] = s0 + i;
                cLen[base + c] = (n - i < CHUNK) ? (n - i) : CHUNK;
            }
        }
    }
}

// ---------------- K5: gather x into sorted bf16 rows + zero pads ----------------
__global__ void k_gather(const float* __restrict__ x, const int* __restrict__ perm,
                         unsigned short* __restrict__ Xs, unsigned short* __restrict__ SHb,
                         unsigned short* __restrict__ Yb) {
    int r = blockIdx.x, tid = threadIdx.x;
    if (r < TOKS) {
        int tok = perm[r];
        floatx4 v = __builtin_nontemporal_load(
            (const floatx4*)(x + (size_t)tok * 1024 + tid * 4));
        ushort4 o;
        o.x = f2bf(v[0]); o.y = f2bf(v[1]); o.z = f2bf(v[2]); o.w = f2bf(v[3]);
        *(ushort4*)(Xs + (size_t)r * 1024 + tid * 4) = o;
    } else {
        ushort4 z = {0, 0, 0, 0};
        *(ushort4*)(Xs + (size_t)r * 1024 + tid * 4) = z;
        if (tid < 128) *(ushort4*)(SHb + (size_t)r * 512 + tid * 4) = z;
        if (tid < 64)  *(ushort4*)(Yb + (size_t)r * 256 + tid * 4) = z;
    }
}

// ---------------- MFMA grouped GEMM, BM=128 BN=64 BK=32, 3-buf pipeline ----------------
// MODE 0: A=Xs (K=1024), B=W12: col0<256 -> Ub fp16; else silu -> SHb bf16
// MODE 1: A=SHb (K=512), B=Wso: region col0>>8 -> fp16 gates
// MODE 2: A=Yb (K=256),  B=Wo : scatter fp32 out via perm (nt stores)
// 256 thr / 4 waves (2M x 2N; per-wave 64x32, acc[4][2]); 3 gl_lds/thread/step,
// vmcnt(3) steady; LDS 36KB -> 4 blk/CU; T5 setprio around MFMA cluster.
template<int MODE, int KD>
__global__ __launch_bounds__(256, 4)
void k_mfma(const unsigned short* __restrict__ A, const unsigned short* __restrict__ Bw,
            const int* __restrict__ perm, const float* __restrict__ dparam,
            half_t* __restrict__ Ub, unsigned short* __restrict__ SHb,
            half_t* __restrict__ Aa, half_t* __restrict__ Wg,
            half_t* __restrict__ Cc, half_t* __restrict__ Sk,
            float* __restrict__ out,
            const int* __restrict__ tileE, const int* __restrict__ tileS,
            const int* __restrict__ tileR, const int* __restrict__ meta) {
    const int mt = blockIdx.x;
    if (mt >= meta[0]) return;
    const int e = tileE[mt], pos0 = tileS[mt], rows = tileR[mt];
    const int col0 = blockIdx.y * 64;
    const int tid = threadIdx.x;
    const int w = tid >> 6, lane = tid & 63, quad = lane >> 4, l15 = lane & 15;
    const int wm = w & 1, wn = w >> 1;          // 2M x 2N wave grid
    constexpr int NOUT = (MODE == 0) ? 768 : 1024;
    constexpr int NK = KD / 32;

    // triple-buffered: A [3][128][32], B [3][64][32] bf16 (12KB/buf set, 36KB)
    __shared__ unsigned short As[3][128 * 32];
    __shared__ unsigned short Bs[3][64 * 32];

    const int r0 = tid >> 2;                    // 0..63
    // pre-swizzled global chunk: chunk' = (tid&3) ^ ((row>>1)&3)
    const int c8s = ((tid & 3) ^ ((tid >> 3) & 3)) * 8;
    const unsigned short* ga = A + (size_t)(pos0 + r0) * KD + c8s;
    const unsigned short* gb = Bw + ((size_t)e * NOUT + col0 + r0) * KD + c8s;

    // fragment read offsets with matching XOR swizzle ((row>>1)&3 == (l15>>1)&3)
    const int sq = (quad ^ ((l15 >> 1) & 3)) * 8;
    int aoff[4], boff[2];
    #pragma unroll
    for (int i = 0; i < 4; i++) aoff[i] = (wm * 64 + i * 16 + l15) * 32 + sq;
    #pragma unroll
    for (int j = 0; j < 2; j++) boff[j] = (wn * 32 + j * 16 + l15) * 32 + sq;

    floatx4 acc[4][2] = {};

    // stage one BK=32 tile: A rows 0-63 and 64-127 (2 passes), B rows 0-63.
    #define STAGE(buf, k0) do { \
        gl_lds16(ga + (k0),                    As[buf] + w * 512); \
        gl_lds16(ga + (size_t)64 * KD + (k0),  As[buf] + 2048 + w * 512); \
        gl_lds16(gb + (k0),                    Bs[buf] + w * 512); \
    } while (0)

    STAGE(0, 0);                      // 3 outstanding
    STAGE(1, 32);                     // 6 outstanding
    int cur = 0, pre = 2;
    for (int kt = 0; kt < NK; kt++) {
        if (kt < NK - 1) {
            asm volatile("s_waitcnt vmcnt(3)" ::: "memory");   // stage(kt) landed
        } else {
            asm volatile("s_waitcnt vmcnt(0)" ::: "memory");
        }
        __builtin_amdgcn_s_barrier();          // all waves' stage(kt) landed; prev reads drained
        asm volatile("" ::: "memory");
        if (kt + 2 < NK) STAGE(pre, (kt + 2) * 32);   // 2-deep prefetch, distinct buffer
        short8 af[4], bf[2];
        #pragma unroll
        for (int i = 0; i < 4; i++) af[i] = *(const short8*)(As[cur] + aoff[i]);
        #pragma unroll
        for (int j = 0; j < 2; j++) bf[j] = *(const short8*)(Bs[cur] + boff[j]);
        __builtin_amdgcn_s_setprio(1);
        #pragma unroll
        for (int i = 0; i < 4; i++)
            #pragma unroll
            for (int j = 0; j < 2; j++)
                acc[i][j] = __builtin_amdgcn_mfma_f32_16x16x32_bf16(af[i], bf[j], acc[i][j], 0, 0, 0);
        __builtin_amdgcn_s_setprio(0);
        asm volatile("s_waitcnt lgkmcnt(0)" ::: "memory");
        __builtin_amdgcn_sched_barrier(0);
        cur = (cur == 2) ? 0 : cur + 1;
        pre = (pre == 2) ? 0 : pre + 1;
    }
    #undef STAGE
    asm volatile("" ::: "memory");             // keep epilogue loads out of the loop

    // epilogue: per 16x16 tile, col = l15 (n), row = quad*4 + reg (m)
    #pragma unroll
    for (int i = 0; i < 4; i++) {
        #pragma unroll
        for (int r = 0; r < 4; r++) {
            int m = wm * 64 + i * 16 + quad * 4 + r;
            if (m >= rows) continue;
            size_t row = (size_t)(pos0 + m);
            if (MODE == 0) {
                if (col0 < 256) {
                    #pragma unroll
                    for (int j = 0; j < 2; j++) {
                        int n = col0 + wn * 32 + j * 16 + l15;
                        Ub[row * 256 + n] = (half_t)acc[i][j][r];
                    }
                } else {
                    #pragma unroll
                    for (int j = 0; j < 2; j++) {
                        int n = col0 - 256 + wn * 32 + j * 16 + l15;
                        float v = acc[i][j][r];
                        SHb[row * 512 + n] = f2bf(v * sigm(v));
                    }
                }
            } else if (MODE == 1) {
                int region = col0 >> 8;  // block-uniform
                #pragma unroll
                for (int j = 0; j < 2; j++) {
                    int n0 = (col0 & 255) + wn * 32 + j * 16 + l15;
                    size_t idx = row * 256 + (size_t)n0;
                    float v = acc[i][j][r];
                    if (region == 0) {
                        Aa[idx] = (half_t)sigm(v);
                    } else if (region == 1) {
                        Wg[idx] = (half_t)(ftanh(v) * (float)Ub[idx]);
                    } else if (region == 2) {
                        Cc[idx] = (half_t)ftanh(v);
                    } else {
                        Sk[idx] = (half_t)(dparam[e * 256 + n0] * sigm(v) * (float)Ub[idx]);
                    }
                }
            } else {
                int tok = perm[row];
                #pragma unroll
                for (int j = 0; j < 2; j++) {
                    int n = col0 + wn * 32 + j * 16 + l15;
                    __builtin_nontemporal_store(acc[i][j][r], &out[(size_t)tok * 1024 + n]);
                }
            }
        }
    }
}

// ---------------- K8a: chunk-local affine composition ----------------
__global__ void k_scanA(const half_t* __restrict__ Aa, const half_t* __restrict__ Wg,
                        const int* __restrict__ cStart, const int* __restrict__ cLen,
                        const int* __restrict__ meta,
                        float* __restrict__ SA, float* __restrict__ SQ) {
    int id = blockIdx.x;
    if (id >= meta[1]) return;
    int t = threadIdx.x;
    int s0 = cStart[id], L = cLen[id];
    size_t idx = (size_t)s0 * 256 + t;
    float p = 1.0f, q = 0.0f;
    if (L == CHUNK) {
        #pragma unroll
        for (int i = 0; i < CHUNK; i++) {
            float a = (float)Aa[idx + (size_t)i * 256], ww = (float)Wg[idx + (size_t)i * 256];
            q = a * q + ww;
            p *= a;
        }
    } else {
        for (int i = 0; i < L; i++) {
            float a = (float)Aa[idx], ww = (float)Wg[idx];
            q = a * q + ww;
            p *= a;
            idx += 256;
        }
    }
    SA[(size_t)id * 256 + t] = p;
    SQ[(size_t)id * 256 + t] = q;
}

// ---------------- K8bc: h_in recompose (folded scanB) + re-scan, emit y ----------------
__global__ void k_scanC(const half_t* __restrict__ Aa, const half_t* __restrict__ Wg,
                        const half_t* __restrict__ Cc, const half_t* __restrict__ Sk,
                        const int* __restrict__ cGrp, const int* __restrict__ cStart,
                        const int* __restrict__ cLen, const int* __restrict__ gBase,
                        const float* __restrict__ SA, const float* __restrict__ SQ,
                        const int* __restrict__ meta,
                        unsigned short* __restrict__ Yb) {
    int id = blockIdx.x;
    if (id >= meta[1]) return;
    int t = threadIdx.x;
    int g = cGrp[id];
    int base = gBase[g];
    int c = id - base;
    float h = 0.0f;
    for (int j = 0; j < c; j++) {
        size_t k = (size_t)(base + j) * 256 + t;
        h = SA[k] * h + SQ[k];
    }
    int s0 = cStart[id], L = cLen[id];
    size_t idx = (size_t)s0 * 256 + t;
    if (L == CHUNK) {
        #pragma unroll
        for (int i = 0; i < CHUNK; i++) {
            size_t k = idx + (size_t)i * 256;
            float a = (float)Aa[k], ww = (float)Wg[k];
            float cc = (float)Cc[k], sk = (float)Sk[k];
            h = a * h + ww;
            Yb[k] = f2bf(cc * h + sk);
        }
    } else {
        for (int i = 0; i < L; i++) {
            float a = (float)Aa[idx], ww = (float)Wg[idx];
            float cc = (float)Cc[idx], sk = (float)Sk[idx];
            h = a * h + ww;
            Yb[idx] = f2bf(cc * h + sk);
            idx += 256;
        }
    }
}

extern "C" void kernel_launch(void* const* d_in, const int* in_sizes, int n_in,
                              void* d_out, int out_size, void* d_ws, size_t ws_size,
                              hipStream_t stream) {
    const float* xin   = (const float*)d_in[0];
    const int*   tok   = (const int*)d_in[1];
    const float* Win   = (const float*)d_in[2];
    const float* Wsin  = (const float*)d_in[3];
    const float* Wsout = (const float*)d_in[4];
    const float* Wout  = (const float*)d_in[5];
    const float* dpar  = (const float*)d_in[6];
    float* out = (float*)d_out;

    size_t off = 0;
    char* base = (char*)d_ws;
    auto alloc = [&](size_t bytes) -> void* {
        void* p = base + off;
        off += (bytes + 255) & ~(size_t)255;
        return p;
    };
    half_t*         Ub  = (half_t*)alloc((size_t)RPAD * NN * 2);
    unsigned short* SHb = (unsigned short*)alloc((size_t)RPAD * HH * 2);
    unsigned short* Xs  = (unsigned short*)alloc((size_t)RPAD * DD * 2);
    unsigned short* Yb  = (unsigned short*)alloc((size_t)RPAD * NN * 2);
    half_t* Aa = (half_t*)alloc((size_t)TOKS * NN * 2);
    half_t* Wg = (half_t*)alloc((size_t)TOKS * NN * 2);
    half_t* Cc = (half_t*)alloc((size_t)TOKS * NN * 2);
    half_t* Sk = (half_t*)alloc((size_t)TOKS * NN * 2);
    unsigned short* W12 = (unsigned short*)alloc((size_t)8 * 768 * 1024 * 2);
    unsigned short* Wso = (unsigned short*)alloc((size_t)8 * 1024 * 512 * 2);
    unsigned short* Wo  = (unsigned short*)alloc((size_t)8 * 1024 * 256 * 2);
    float* SA  = (float*)alloc((size_t)MAXCHUNKS * 256 * 4);
    float* SQ  = (float*)alloc((size_t)MAXCHUNKS * 256 * 4);
    int* perm   = (int*)alloc(TOKS * 4);
    int* tileE  = (int*)alloc(MAXTILES * 4);
    int* tileS  = (int*)alloc(MAXTILES * 4);
    int* tileR  = (int*)alloc(MAXTILES * 4);
    int* cGrp   = (int*)alloc(MAXCHUNKS * 4);
    int* cStart = (int*)alloc(MAXCHUNKS * 4);
    int* cLen   = (int*)alloc(MAXCHUNKS * 4);
    int* gBase  = (int*)alloc(64 * 4);
    int* meta   = (int*)alloc(16 * 4);

    k_scatter<<<8 + CVTBLKS, 256, 0, stream>>>(tok, perm, tileE, tileS, tileR,
                                               cGrp, cStart, cLen, gBase, meta,
                                               Win, Wsin, Wsout, Wout, W12, Wso, Wo);
    k_gather<<<RPAD, 256, 0, stream>>>(xin, perm, Xs, SHb, Yb);

    k_mfma<0, 1024><<<dim3(MAXTILES, 12), 256, 0, stream>>>(Xs, W12, perm, dpar,
        Ub, SHb, Aa, Wg, Cc, Sk, out, tileE, tileS, tileR, meta);
    k_mfma<1, 512><<<dim3(MAXTILES, 16), 256, 0, stream>>>(SHb, Wso, perm, dpar,
        Ub, SHb, Aa, Wg, Cc, Sk, out, tileE, tileS, tileR, meta);

    k_scanA<<<MAXCHUNKS, 256, 0, stream>>>(Aa, Wg, cStart, cLen, meta, SA, SQ);
    k_scanC<<<MAXCHUNKS, 256, 0, stream>>>(Aa, Wg, Cc, Sk, cGrp, cStart, cLen,
                                           gBase, SA, SQ, meta, Yb);

    k_mfma<2, 256><<<dim3(MAXTILES, 16), 256, 0, stream>>>(Yb, Wo, perm, dpar,
        Ub, SHb, Aa, Wg, Cc, Sk, out, tileE, tileS, tileR, meta);
}